// Round 10
// baseline (710.735 us; speedup 1.0000x reference)
//
#include <hip/hip_runtime.h>
#include <hip/hip_bf16.h>

typedef unsigned int uint32;
typedef __attribute__((ext_vector_type(8))) short bs8;     // 8 bf16 = 4 VGPR (MFMA A/B frag)
typedef __attribute__((ext_vector_type(16))) float f32x16; // MFMA C/D frag

#define BATCH 32
#define NIN   2048
#define DIN   16
#define NCAP  64
#define DCAP  32
#define ROW   2048   // NCAP*DCAP

// single-instruction packed f32->bf16x2 (RNE on gfx950); lo -> bits[15:0]
__device__ __forceinline__ uint32 cvt_pk_bf16(float lo, float hi){
    uint32 r;
    asm("v_cvt_pk_bf16_f32 %0, %1, %2" : "=v"(r) : "v"(lo), "v"(hi));
    return r;
}
__device__ __forceinline__ float bf_lo(uint32 w){ return __uint_as_float(w << 16); }
__device__ __forceinline__ float bf_hi(uint32 w){ return __uint_as_float(w & 0xffff0000u); }

// ---------------------------------------------------------------------------
// K1 v6 (MFMA): u[b,n,c,e] = sum_d x[b,n,d]*W[n,c,d,e] + B[c,e]  (bf16 store)
//   One v_mfma_f32_32x32x16_bf16 per (n, c) tile: M=batch(32), N=e(32), K=d(16).
//   A-frag: x bf16 (lane: b=l&31, d=(l>>5)*8+j)    [k-mapping shared with B ->
//   B-frag: W bf16 (lane: e=l&31, d=(l>>5)*8+j)     sum-over-k is invariant]
//   C-in  : bias[c,e] broadcast over all 16 rows.
//   D     : row b=(r&3)+8*(r>>2)+4*(l>>5), col e=l&31  [HW-verified layout]
//   s1 partials accumulated in f32 across the chunk's 8 n, stored bf16.
// Block 256 = 4 waves; wave owns (4 caps x 8 n). grid = (4 cap16-groups, 256).
// ---------------------------------------------------------------------------
__global__ __launch_bounds__(256)
void k1_predict(const float* __restrict__ x, const float* __restrict__ W,
                const float* __restrict__ Bc, __hip_bfloat16* __restrict__ u,
                ushort* __restrict__ part)
{
    __shared__ ushort xbf[8 * 32 * 16];   // [i][b][d] bf16, 8 KB
    const int t     = threadIdx.x;
    const int cg4   = blockIdx.x;         // 0..3 : group of 16 capsules
    const int chunk = blockIdx.y;         // 0..255 : 8 n each
    const int n0    = chunk * 8;
    const int wv    = t >> 6;
    const int lane  = t & 63;
    const int eL    = lane & 31;          // e (B col / C col) ; also b for A
    const int hL    = lane >> 5;          // k-half selector

    // stage x[0..31, n0..n0+7, 0..15] -> bf16 LDS [i][b][d]
    #pragma unroll
    for (int q = 0; q < 4; ++q) {
        const int f = t * 16 + q * 4;                 // element in [i][b][d]
        const int i = f >> 9, b = (f >> 4) & 31, d = f & 15;
        const float4 xv = *(const float4*)(x + ((size_t)b * NIN + n0 + i) * DIN + d);
        uint2 pk;
        pk.x = cvt_pk_bf16(xv.x, xv.y);
        pk.y = cvt_pk_bf16(xv.z, xv.w);
        *(uint2*)(xbf + f) = pk;
    }
    __syncthreads();

    // A fragments for the 8 n's: lane reads x[b=eL][d = hL*8 .. hL*8+7]
    bs8 afrag[8];
    #pragma unroll
    for (int i = 0; i < 8; ++i)
        afrag[i] = *(const bs8*)(xbf + (i * 32 + eL) * 16 + hL * 8);

    const int c0 = cg4 * 16 + wv * 4;

    #pragma unroll
    for (int cc = 0; cc < 4; ++cc) {
        const int c = c0 + cc;
        const float biasv = Bc[c * DCAP + eL];
        f32x16 cin;
        #pragma unroll
        for (int r = 0; r < 16; ++r) cin[r] = biasv;
        f32x16 sacc;
        #pragma unroll
        for (int r = 0; r < 16; ++r) sacc[r] = 0.f;

        for (int i = 0; i < 8; ++i) {
            const int n = n0 + i;
            // B-frag: lane needs W[n, c, d = hL*8+j, e=eL], j=0..7 (stride 32 f32)
            const float* wp = W + (size_t)n * (NCAP * DIN * DCAP) + c * (DIN * DCAP)
                            + hL * 8 * DCAP + eL;
            float wv8[8];
            #pragma unroll
            for (int j = 0; j < 8; ++j) wv8[j] = wp[j * DCAP];
            union { uint32 q[4]; bs8 v; } bfr;
            #pragma unroll
            for (int qq = 0; qq < 4; ++qq)
                bfr.q[qq] = cvt_pk_bf16(wv8[2*qq], wv8[2*qq+1]);

            f32x16 dreg = __builtin_amdgcn_mfma_f32_32x32x16_bf16(
                              afrag[i], bfr.v, cin, 0, 0, 0);

            __hip_bfloat16* ub = u + (size_t)(hL * 4) * (NIN * ROW)
                               + (size_t)n * ROW + c * DCAP + eL;
            #pragma unroll
            for (int r = 0; r < 16; ++r) {
                sacc[r] += dreg[r];
                const int br = (r & 3) + 8 * (r >> 2);   // + 4*hL in base
                ub[(size_t)br * (NIN * ROW)] = __float2bfloat16(dreg[r]);
            }
        }

        // s1 partial (bf16): part[b][chunk][c*32+e]
        ushort* pb = part + ((size_t)(hL * 4) * 256 + chunk) * ROW + c * DCAP + eL;
        #pragma unroll
        for (int r = 0; r < 16; ++r) {
            const int br = (r & 3) + 8 * (r >> 2);
            union { __hip_bfloat16 h; ushort us; } cv;
            cv.h = __float2bfloat16(sacc[r]);
            pb[(size_t)br * (256 * ROW)] = cv.us;
        }
    }
}

// ---------------------------------------------------------------------------
// K2: s[b,p0..p0+3] = factor * sum_ch part[b][ch][p]; v = squash(s);
//     V = (first ? v : V+v); if(out) out = v.  part bf16 or f32 per flag.
// grid = (8, BATCH), block 64; thread owns 4 consecutive p (e-group = 8 lanes)
// ---------------------------------------------------------------------------
__global__ __launch_bounds__(64)
void k2_squash(const void* __restrict__ partv, int nch, int isbf16, float factor,
               float* __restrict__ V, float* __restrict__ out, int first)
{
    const int t  = threadIdx.x;
    const int b  = blockIdx.y;
    const int p0 = (blockIdx.x * 64 + t) * 4;

    float a0 = 0.f, a1 = 0.f, a2 = 0.f, a3 = 0.f;
    if (isbf16) {
        const ushort* pp = (const ushort*)partv;
        #pragma unroll 4
        for (int ch = 0; ch < nch; ++ch) {
            const uint2 v = *(const uint2*)(pp + ((size_t)b * nch + ch) * ROW + p0);
            a0 += bf_lo(v.x); a1 += bf_hi(v.x);
            a2 += bf_lo(v.y); a3 += bf_hi(v.y);
        }
    } else {
        const float* pp = (const float*)partv;
        #pragma unroll 4
        for (int ch = 0; ch < nch; ++ch) {
            const float4 v = *(const float4*)(pp + ((size_t)b * nch + ch) * ROW + p0);
            a0 += v.x; a1 += v.y; a2 += v.z; a3 += v.w;
        }
    }
    a0 *= factor; a1 *= factor; a2 *= factor; a3 *= factor;

    float nsq = a0*a0 + a1*a1 + a2*a2 + a3*a3;
    nsq += __shfl_xor(nsq, 1);
    nsq += __shfl_xor(nsq, 2);
    nsq += __shfl_xor(nsq, 4);                       // 8 lanes × 4 = 32 e
    const float scale = nsq / ((1.f + nsq) * sqrtf(nsq + 1e-9f));
    const float v0 = scale*a0, v1 = scale*a1, v2 = scale*a2, v3 = scale*a3;

    const size_t idx = (size_t)b * ROW + p0;
    float4 Vn;
    if (first) Vn = make_float4(v0, v1, v2, v3);
    else {
        const float4 old = *(const float4*)(V + idx);
        Vn = make_float4(old.x+v0, old.y+v1, old.z+v2, old.w+v3);
    }
    *(float4*)(V + idx) = Vn;
    if (out) *(float4*)(out + idx) = make_float4(v0, v1, v2, v3);
}

// ---------------------------------------------------------------------------
// K3 sweep, COALESCED (R5-proven, unchanged): wave reads u row contiguously;
// lane holds e-slice es=(l&3)*8 of capsules q*16+(l>>2). Quad-shfl logit
// reduce, wave softmax denom (*4), no max-sub. 4-wave blocks, LDS c*33+e
// reduce, f32 partials nch=32.  grid = (32 n-chunks of 64, BATCH), block 256.
// ---------------------------------------------------------------------------
__global__ __launch_bounds__(256)
void k3_sweep(const __hip_bfloat16* __restrict__ u, const float* __restrict__ V,
              float* __restrict__ part)
{
    __shared__ float red[4 * 2112];                  // [wave][c*33+e]
    const int t     = threadIdx.x;
    const int lane  = t & 63;
    const int wv    = t >> 6;
    const int chunk = blockIdx.x;
    const int b     = blockIdx.y;

    const int qr = lane >> 2;                        // 0..15: capsule-in-quarter
    const int es = (lane & 3) * 8;                   // e-slice start

    float vr[4][8];
    #pragma unroll
    for (int q = 0; q < 4; ++q) {
        const float* vp = V + (size_t)b * ROW + (q * 16 + qr) * DCAP + es;
        const float4 v0 = *(const float4*)(vp);
        const float4 v1 = *(const float4*)(vp + 4);
        vr[q][0]=v0.x; vr[q][1]=v0.y; vr[q][2]=v0.z; vr[q][3]=v0.w;
        vr[q][4]=v1.x; vr[q][5]=v1.y; vr[q][6]=v1.z; vr[q][7]=v1.w;
    }

    float sacc[4][8];
    #pragma unroll
    for (int q = 0; q < 4; ++q)
        #pragma unroll
        for (int j = 0; j < 8; ++j) sacc[q][j] = 0.f;

    const int nbase = chunk * 64 + wv * 16;
    const __hip_bfloat16* ubase = u + ((size_t)b * NIN + nbase) * ROW + lane * 8;

    uint4 A[4];
    #pragma unroll
    for (int q = 0; q < 4; ++q)
        A[q] = *(const uint4*)(ubase + q * 512);

    for (int it = 0; it < 16; ++it) {
        uint4 Bn[4];
        if (it < 15) {
            const __hip_bfloat16* un = ubase + (size_t)(it + 1) * ROW;
            #pragma unroll
            for (int q = 0; q < 4; ++q)
                Bn[q] = *(const uint4*)(un + q * 512);
        }

        float p[4];
        #pragma unroll
        for (int q = 0; q < 4; ++q) {
            const uint32 w0 = A[q].x, w1 = A[q].y, w2 = A[q].z, w3 = A[q].w;
            float l0 = bf_lo(w0) * vr[q][0];
            float l1 = bf_hi(w0) * vr[q][1];
            l0 = fmaf(bf_lo(w1), vr[q][2], l0);
            l1 = fmaf(bf_hi(w1), vr[q][3], l1);
            l0 = fmaf(bf_lo(w2), vr[q][4], l0);
            l1 = fmaf(bf_hi(w2), vr[q][5], l1);
            l0 = fmaf(bf_lo(w3), vr[q][6], l0);
            l1 = fmaf(bf_hi(w3), vr[q][7], l1);
            p[q] = l0 + l1;
        }
        #pragma unroll
        for (int q = 0; q < 4; ++q) {
            p[q] += __shfl_xor(p[q], 1);
            p[q] += __shfl_xor(p[q], 2);
        }
        float e0 = __expf(p[0]), e1 = __expf(p[1]),
              e2 = __expf(p[2]), e3 = __expf(p[3]);
        float s = (e0 + e1) + (e2 + e3);
        s += __shfl_xor(s, 4);
        s += __shfl_xor(s, 8);
        s += __shfl_xor(s, 16);
        s += __shfl_xor(s, 32);                      // s = 4 * sum_c exp
        const float inv = 4.0f / s;
        const float cw[4] = {e0 * inv, e1 * inv, e2 * inv, e3 * inv};

        #pragma unroll
        for (int q = 0; q < 4; ++q) {
            const uint32 w0 = A[q].x, w1 = A[q].y, w2 = A[q].z, w3 = A[q].w;
            const float c = cw[q];
            sacc[q][0] = fmaf(c, bf_lo(w0), sacc[q][0]);
            sacc[q][1] = fmaf(c, bf_hi(w0), sacc[q][1]);
            sacc[q][2] = fmaf(c, bf_lo(w1), sacc[q][2]);
            sacc[q][3] = fmaf(c, bf_hi(w1), sacc[q][3]);
            sacc[q][4] = fmaf(c, bf_lo(w2), sacc[q][4]);
            sacc[q][5] = fmaf(c, bf_hi(w2), sacc[q][5]);
            sacc[q][6] = fmaf(c, bf_lo(w3), sacc[q][6]);
            sacc[q][7] = fmaf(c, bf_hi(w3), sacc[q][7]);
        }

        if (it < 15) {
            #pragma unroll
            for (int q = 0; q < 4; ++q) A[q] = Bn[q];
        }
    }

    #pragma unroll
    for (int q = 0; q < 4; ++q) {
        const int c = q * 16 + qr;
        #pragma unroll
        for (int j = 0; j < 8; ++j)
            red[wv * 2112 + c * 33 + es + j] = sacc[q][j];
    }
    __syncthreads();
    #pragma unroll
    for (int k = 0; k < 8; ++k) {
        const int pp = t + 256 * k;
        const int c = pp >> 5, e = pp & 31;
        part[((size_t)b * 32 + chunk) * ROW + pp] =
            red[0*2112 + c*33+e] + red[1*2112 + c*33+e] +
            red[2*2112 + c*33+e] + red[3*2112 + c*33+e];
    }
}

// ---------------------------------------------------------------------------
extern "C" void kernel_launch(void* const* d_in, const int* in_sizes, int n_in,
                              void* d_out, int out_size, void* d_ws, size_t ws_size,
                              hipStream_t stream)
{
    const float* x  = (const float*)d_in[0];
    const float* W  = (const float*)d_in[1];
    const float* Bc = (const float*)d_in[2];
    float* out = (float*)d_out;

    const size_t off_u    = 0;                       // u: 32*2048*2048 bf16 = 256 MiB
    const size_t off_part = 268435456;               // part: 32 MiB max
    const size_t off_V    = off_part + 33554432;     // V: 32*64*32 f32
    const size_t need     = off_V + 262144;
    if (ws_size < need) return;

    __hip_bfloat16* u  = (__hip_bfloat16*)((char*)d_ws + off_u);
    ushort* part_bf    = (ushort*)((char*)d_ws + off_part);
    float*  part_f     = (float*)((char*)d_ws + off_part);   // aliased: consumed before k3 writes
    float*  V          = (float*)((char*)d_ws + off_V);

    // iter 1: u via MFMA + uniform-softmax s1 fused (bf16 partials, 256 chunks)
    k1_predict<<<dim3(4, 256), 256, 0, stream>>>(x, W, Bc, u, part_bf);
    k2_squash <<<dim3(8, BATCH), 64, 0, stream>>>(part_bf, 256, 1, 1.0f/64.0f, V, nullptr, 1);
    // iter 2: logits = u.V (V=v1), softmax, s2
    k3_sweep  <<<dim3(32, BATCH), 256, 0, stream>>>(u, V, part_f);
    k2_squash <<<dim3(8, BATCH), 64, 0, stream>>>(part_f, 32, 0, 1.0f, V, nullptr, 0);
    // iter 3: logits = u.(v1+v2), softmax, s3 -> v3 = output
    k3_sweep  <<<dim3(32, BATCH), 256, 0, stream>>>(u, V, part_f);
    k2_squash <<<dim3(8, BATCH), 64, 0, stream>>>(part_f, 32, 0, 1.0f, V, out, 0);
}

// Round 11
// 335.905 us; speedup vs baseline: 2.1159x; 2.1159x over previous
//
#include <hip/hip_runtime.h>
#include <hip/hip_bf16.h>

typedef unsigned int uint32;

#define BATCH 32
#define NIN   2048
#define DIN   16
#define NCAP  64
#define DCAP  32
#define ROW   2048   // NCAP*DCAP

// single-instruction packed f32->bf16x2 (RNE on gfx950); lo -> bits[15:0]
__device__ __forceinline__ uint32 cvt_pk_bf16(float lo, float hi){
    uint32 r;
    asm("v_cvt_pk_bf16_f32 %0, %1, %2" : "=v"(r) : "v"(lo), "v"(hi));
    return r;
}
__device__ __forceinline__ float bf_lo(uint32 w){ return __uint_as_float(w << 16); }
__device__ __forceinline__ float bf_hi(uint32 w){ return __uint_as_float(w & 0xffff0000u); }

// ---------------------------------------------------------------------------
// K1 v7: R5 shape (thread = (cap, 4e) x 32 b) with two occupancy/issue fixes:
//  (a) s1 accumulator packed bf16 (spk[32][2] = 64 VGPR, R9-verified numerics)
//      -> ~150 VGPR total -> 3 waves/SIMD (was 2 with f32 sacc[32][4]).
//  (b) x read via wave-UNIFORM loads (no threadIdx in address) -> compiler
//      promotes to s_load + SGPR-operand v_fma; kills the LDS array, staging
//      loop, __syncthreads, and 1024 ds_read_b128/thread of issue+lgkm work.
// grid = (2 ce-halves, 256 chunks of 8 n), block 256.
// Tripwires: LDS_Block_Size must be 0; WRITE_SIZE must stay ~294912 KB.
// ---------------------------------------------------------------------------
__global__ __launch_bounds__(256)
void k1_predict(const float* __restrict__ x, const float* __restrict__ W,
                const float* __restrict__ Bc, __hip_bfloat16* __restrict__ u,
                ushort* __restrict__ part)
{
    const int t     = threadIdx.x;
    const int half  = blockIdx.x;                   // ce-half
    const int chunk = blockIdx.y;                   // 0..255, 8 n each
    const int n0    = chunk * 8;
    const int cl    = t >> 3;                       // 0..31 local capsule
    const int e0    = (t & 7) * 4;                  // 4 consecutive e
    const int cg    = half * 32 + cl;               // global capsule

    const float4 bias = *(const float4*)(Bc + cg * DCAP + e0);

    uint32 spk[32][2];                              // packed bf16 s1 accumulator
    #pragma unroll
    for (int b = 0; b < 32; ++b) { spk[b][0] = 0u; spk[b][1] = 0u; }

    const float* wbase = W + (size_t)cg * (DIN * DCAP) + e0;

    for (int i = 0; i < 8; ++i) {
        const int n = n0 + i;
        float4 w[16];
        {
            const float* wp = wbase + (size_t)n * (NCAP * DIN * DCAP);
            #pragma unroll
            for (int d = 0; d < 16; ++d) w[d] = *(const float4*)(wp + d * DCAP);
        }
        __hip_bfloat16* ub = u + (size_t)n * ROW + cg * DCAP + e0;
        const float* xrow = x + (size_t)n * DIN;    // + b*NIN*DIN per b (uniform)

        #pragma unroll
        for (int bi = 0; bi < 32; ++bi) {
            // wave-uniform x reads -> s_load + SGPR-operand FMAs
            const float* xr = xrow + (size_t)bi * (NIN * DIN);
            float4 uv = bias;
            #pragma unroll
            for (int d4 = 0; d4 < 4; ++d4) {
                const float4 xv = *(const float4*)(xr + d4 * 4);   // uniform
                uv.x = fmaf(xv.x, w[d4*4+0].x, uv.x);
                uv.y = fmaf(xv.x, w[d4*4+0].y, uv.y);
                uv.z = fmaf(xv.x, w[d4*4+0].z, uv.z);
                uv.w = fmaf(xv.x, w[d4*4+0].w, uv.w);
                uv.x = fmaf(xv.y, w[d4*4+1].x, uv.x);
                uv.y = fmaf(xv.y, w[d4*4+1].y, uv.y);
                uv.z = fmaf(xv.y, w[d4*4+1].z, uv.z);
                uv.w = fmaf(xv.y, w[d4*4+1].w, uv.w);
                uv.x = fmaf(xv.z, w[d4*4+2].x, uv.x);
                uv.y = fmaf(xv.z, w[d4*4+2].y, uv.y);
                uv.z = fmaf(xv.z, w[d4*4+2].z, uv.z);
                uv.w = fmaf(xv.z, w[d4*4+2].w, uv.w);
                uv.x = fmaf(xv.w, w[d4*4+3].x, uv.x);
                uv.y = fmaf(xv.w, w[d4*4+3].y, uv.y);
                uv.z = fmaf(xv.w, w[d4*4+3].z, uv.z);
                uv.w = fmaf(xv.w, w[d4*4+3].w, uv.w);
            }
            uint2 pk;
            pk.x = cvt_pk_bf16(uv.x, uv.y);
            pk.y = cvt_pk_bf16(uv.z, uv.w);
            *(uint2*)(ub + (size_t)bi * (NIN * ROW)) = pk;
            spk[bi][0] = cvt_pk_bf16(bf_lo(spk[bi][0]) + uv.x,
                                     bf_hi(spk[bi][0]) + uv.y);
            spk[bi][1] = cvt_pk_bf16(bf_lo(spk[bi][1]) + uv.z,
                                     bf_hi(spk[bi][1]) + uv.w);
        }
    }

    #pragma unroll
    for (int b = 0; b < 32; ++b) {
        uint2 pk; pk.x = spk[b][0]; pk.y = spk[b][1];
        *(uint2*)(part + ((size_t)b * 256 + chunk) * ROW + cg * DCAP + e0) = pk;
    }
}

// ---------------------------------------------------------------------------
// K2: s[b,p0..p0+3] = factor * sum_ch part[b][ch][p]; v = squash(s);
//     V = (first ? v : V+v); if(out) out = v.  part bf16 or f32 per flag.
// grid = (8, BATCH), block 64; thread owns 4 consecutive p (e-group = 8 lanes)
// ---------------------------------------------------------------------------
__global__ __launch_bounds__(64)
void k2_squash(const void* __restrict__ partv, int nch, int isbf16, float factor,
               float* __restrict__ V, float* __restrict__ out, int first)
{
    const int t  = threadIdx.x;
    const int b  = blockIdx.y;
    const int p0 = (blockIdx.x * 64 + t) * 4;

    float a0 = 0.f, a1 = 0.f, a2 = 0.f, a3 = 0.f;
    if (isbf16) {
        const ushort* pp = (const ushort*)partv;
        #pragma unroll 4
        for (int ch = 0; ch < nch; ++ch) {
            const uint2 v = *(const uint2*)(pp + ((size_t)b * nch + ch) * ROW + p0);
            a0 += bf_lo(v.x); a1 += bf_hi(v.x);
            a2 += bf_lo(v.y); a3 += bf_hi(v.y);
        }
    } else {
        const float* pp = (const float*)partv;
        #pragma unroll 4
        for (int ch = 0; ch < nch; ++ch) {
            const float4 v = *(const float4*)(pp + ((size_t)b * nch + ch) * ROW + p0);
            a0 += v.x; a1 += v.y; a2 += v.z; a3 += v.w;
        }
    }
    a0 *= factor; a1 *= factor; a2 *= factor; a3 *= factor;

    float nsq = a0*a0 + a1*a1 + a2*a2 + a3*a3;
    nsq += __shfl_xor(nsq, 1);
    nsq += __shfl_xor(nsq, 2);
    nsq += __shfl_xor(nsq, 4);                       // 8 lanes × 4 = 32 e
    const float scale = nsq / ((1.f + nsq) * sqrtf(nsq + 1e-9f));
    const float v0 = scale*a0, v1 = scale*a1, v2 = scale*a2, v3 = scale*a3;

    const size_t idx = (size_t)b * ROW + p0;
    float4 Vn;
    if (first) Vn = make_float4(v0, v1, v2, v3);
    else {
        const float4 old = *(const float4*)(V + idx);
        Vn = make_float4(old.x+v0, old.y+v1, old.z+v2, old.w+v3);
    }
    *(float4*)(V + idx) = Vn;
    if (out) *(float4*)(out + idx) = make_float4(v0, v1, v2, v3);
}

// ---------------------------------------------------------------------------
// K3 sweep, COALESCED (R5-proven, unchanged): wave reads u row contiguously;
// lane holds e-slice es=(l&3)*8 of capsules q*16+(l>>2). Quad-shfl logit
// reduce, wave softmax denom (*4), no max-sub. 4-wave blocks, LDS c*33+e
// reduce, f32 partials nch=32.  grid = (32 n-chunks of 64, BATCH), block 256.
// ---------------------------------------------------------------------------
__global__ __launch_bounds__(256)
void k3_sweep(const __hip_bfloat16* __restrict__ u, const float* __restrict__ V,
              float* __restrict__ part)
{
    __shared__ float red[4 * 2112];                  // [wave][c*33+e]
    const int t     = threadIdx.x;
    const int lane  = t & 63;
    const int wv    = t >> 6;
    const int chunk = blockIdx.x;
    const int b     = blockIdx.y;

    const int qr = lane >> 2;                        // 0..15: capsule-in-quarter
    const int es = (lane & 3) * 8;                   // e-slice start

    float vr[4][8];
    #pragma unroll
    for (int q = 0; q < 4; ++q) {
        const float* vp = V + (size_t)b * ROW + (q * 16 + qr) * DCAP + es;
        const float4 v0 = *(const float4*)(vp);
        const float4 v1 = *(const float4*)(vp + 4);
        vr[q][0]=v0.x; vr[q][1]=v0.y; vr[q][2]=v0.z; vr[q][3]=v0.w;
        vr[q][4]=v1.x; vr[q][5]=v1.y; vr[q][6]=v1.z; vr[q][7]=v1.w;
    }

    float sacc[4][8];
    #pragma unroll
    for (int q = 0; q < 4; ++q)
        #pragma unroll
        for (int j = 0; j < 8; ++j) sacc[q][j] = 0.f;

    const int nbase = chunk * 64 + wv * 16;
    const __hip_bfloat16* ubase = u + ((size_t)b * NIN + nbase) * ROW + lane * 8;

    uint4 A[4];
    #pragma unroll
    for (int q = 0; q < 4; ++q)
        A[q] = *(const uint4*)(ubase + q * 512);

    for (int it = 0; it < 16; ++it) {
        uint4 Bn[4];
        if (it < 15) {
            const __hip_bfloat16* un = ubase + (size_t)(it + 1) * ROW;
            #pragma unroll
            for (int q = 0; q < 4; ++q)
                Bn[q] = *(const uint4*)(un + q * 512);
        }

        float p[4];
        #pragma unroll
        for (int q = 0; q < 4; ++q) {
            const uint32 w0 = A[q].x, w1 = A[q].y, w2 = A[q].z, w3 = A[q].w;
            float l0 = bf_lo(w0) * vr[q][0];
            float l1 = bf_hi(w0) * vr[q][1];
            l0 = fmaf(bf_lo(w1), vr[q][2], l0);
            l1 = fmaf(bf_hi(w1), vr[q][3], l1);
            l0 = fmaf(bf_lo(w2), vr[q][4], l0);
            l1 = fmaf(bf_hi(w2), vr[q][5], l1);
            l0 = fmaf(bf_lo(w3), vr[q][6], l0);
            l1 = fmaf(bf_hi(w3), vr[q][7], l1);
            p[q] = l0 + l1;
        }
        #pragma unroll
        for (int q = 0; q < 4; ++q) {
            p[q] += __shfl_xor(p[q], 1);
            p[q] += __shfl_xor(p[q], 2);
        }
        float e0 = __expf(p[0]), e1 = __expf(p[1]),
              e2 = __expf(p[2]), e3 = __expf(p[3]);
        float s = (e0 + e1) + (e2 + e3);
        s += __shfl_xor(s, 4);
        s += __shfl_xor(s, 8);
        s += __shfl_xor(s, 16);
        s += __shfl_xor(s, 32);                      // s = 4 * sum_c exp
        const float inv = 4.0f / s;
        const float cw[4] = {e0 * inv, e1 * inv, e2 * inv, e3 * inv};

        #pragma unroll
        for (int q = 0; q < 4; ++q) {
            const uint32 w0 = A[q].x, w1 = A[q].y, w2 = A[q].z, w3 = A[q].w;
            const float c = cw[q];
            sacc[q][0] = fmaf(c, bf_lo(w0), sacc[q][0]);
            sacc[q][1] = fmaf(c, bf_hi(w0), sacc[q][1]);
            sacc[q][2] = fmaf(c, bf_lo(w1), sacc[q][2]);
            sacc[q][3] = fmaf(c, bf_hi(w1), sacc[q][3]);
            sacc[q][4] = fmaf(c, bf_lo(w2), sacc[q][4]);
            sacc[q][5] = fmaf(c, bf_hi(w2), sacc[q][5]);
            sacc[q][6] = fmaf(c, bf_lo(w3), sacc[q][6]);
            sacc[q][7] = fmaf(c, bf_hi(w3), sacc[q][7]);
        }

        if (it < 15) {
            #pragma unroll
            for (int q = 0; q < 4; ++q) A[q] = Bn[q];
        }
    }

    #pragma unroll
    for (int q = 0; q < 4; ++q) {
        const int c = q * 16 + qr;
        #pragma unroll
        for (int j = 0; j < 8; ++j)
            red[wv * 2112 + c * 33 + es + j] = sacc[q][j];
    }
    __syncthreads();
    #pragma unroll
    for (int k = 0; k < 8; ++k) {
        const int pp = t + 256 * k;
        const int c = pp >> 5, e = pp & 31;
        part[((size_t)b * 32 + chunk) * ROW + pp] =
            red[0*2112 + c*33+e] + red[1*2112 + c*33+e] +
            red[2*2112 + c*33+e] + red[3*2112 + c*33+e];
    }
}

// ---------------------------------------------------------------------------
extern "C" void kernel_launch(void* const* d_in, const int* in_sizes, int n_in,
                              void* d_out, int out_size, void* d_ws, size_t ws_size,
                              hipStream_t stream)
{
    const float* x  = (const float*)d_in[0];
    const float* W  = (const float*)d_in[1];
    const float* Bc = (const float*)d_in[2];
    float* out = (float*)d_out;

    const size_t off_u    = 0;                       // u: 32*2048*2048 bf16 = 256 MiB
    const size_t off_part = 268435456;               // part: 32 MiB max
    const size_t off_V    = off_part + 33554432;     // V: 32*64*32 f32
    const size_t need     = off_V + 262144;
    if (ws_size < need) return;

    __hip_bfloat16* u  = (__hip_bfloat16*)((char*)d_ws + off_u);
    ushort* part_bf    = (ushort*)((char*)d_ws + off_part);
    float*  part_f     = (float*)((char*)d_ws + off_part);   // aliased: consumed before k3 writes
    float*  V          = (float*)((char*)d_ws + off_V);

    // iter 1: u + uniform-softmax s1 fused (bf16 partials)
    k1_predict<<<dim3(2, 256), 256, 0, stream>>>(x, W, Bc, u, part_bf);
    k2_squash <<<dim3(8, BATCH), 64, 0, stream>>>(part_bf, 256, 1, 1.0f/64.0f, V, nullptr, 1);
    // iter 2: logits = u.V (V=v1), softmax, s2
    k3_sweep  <<<dim3(32, BATCH), 256, 0, stream>>>(u, V, part_f);
    k2_squash <<<dim3(8, BATCH), 64, 0, stream>>>(part_f, 32, 0, 1.0f, V, nullptr, 0);
    // iter 3: logits = u.(v1+v2), softmax, s3 -> v3 = output
    k3_sweep  <<<dim3(32, BATCH), 256, 0, stream>>>(u, V, part_f);
    k2_squash <<<dim3(8, BATCH), 64, 0, stream>>>(part_f, 32, 0, 1.0f, V, out, 0);
}

// Round 12
// 309.728 us; speedup vs baseline: 2.2947x; 1.0845x over previous
//
#include <hip/hip_runtime.h>
#include <hip/hip_bf16.h>

typedef unsigned int uint32;

#define BATCH 32
#define NIN   2048
#define DIN   16
#define NCAP  64
#define DCAP  32
#define ROW   2048   // NCAP*DCAP

// single-instruction packed f32->bf16x2 (RNE on gfx950); lo -> bits[15:0]
__device__ __forceinline__ uint32 cvt_pk_bf16(float lo, float hi){
    uint32 r;
    asm("v_cvt_pk_bf16_f32 %0, %1, %2" : "=v"(r) : "v"(lo), "v"(hi));
    return r;
}
__device__ __forceinline__ float bf_lo(uint32 w){ return __uint_as_float(w << 16); }
__device__ __forceinline__ float bf_hi(uint32 w){ return __uint_as_float(w & 0xffff0000u); }

// ---------------------------------------------------------------------------
// K1 v8: 2-way b-split for occupancy. Thread = (cap, 4e) x 16 b.
//   Regs: spk[16][2]=32 (packed bf16 acc, R9-proven) + w[16] float4=64
//         + addr ~25  =>  ~120 VGPR -> 4 waves/SIMD; grid 1024 blocks
//         = 4 blocks/CU -> occupancy actually doubles (R5's grid capped at 2).
//   Issue mix: 16 W-loads per 1024 FMAs (R7's failed 4-way split was 16/512).
//   Cost: W fetched by both b-half blocks (FETCH may ~2x; latency-bound, ok).
// grid = (2 ce-halves x 2 b-halves, 256 chunks of 8 n), block 256.
// Tripwires: VGPR <= ~135; WRITE_SIZE == 294912 KB (no spill).
// ---------------------------------------------------------------------------
__global__ __launch_bounds__(256)
void k1_predict(const float* __restrict__ x, const float* __restrict__ W,
                const float* __restrict__ Bc, __hip_bfloat16* __restrict__ u,
                ushort* __restrict__ part)
{
    __shared__ float xs[8 * 16 * 16];               // [i][bl][d], 8 KB
    const int t     = threadIdx.x;
    const int half  = blockIdx.x & 1;               // ce-half
    const int bhalf = blockIdx.x >> 1;              // b-half
    const int chunk = blockIdx.y;                   // 0..255, 8 n each
    const int n0    = chunk * 8;
    const int cl    = t >> 3;                       // 0..31 local capsule
    const int e0    = (t & 7) * 4;                  // 4 consecutive e
    const int cg    = half * 32 + cl;               // global capsule
    const int b0    = bhalf * 16;

    // stage x[b0..b0+15, n0..n0+7, 0..15] -> xs[i][bl][d]
    #pragma unroll
    for (int k = 0; k < 2; ++k) {
        const int f = (t + 256 * k) * 4;
        const int i = f >> 8, rem = f & 255, bl = rem >> 4, d = rem & 15;
        *(float4*)(xs + f) =
            *(const float4*)(x + ((size_t)(b0 + bl) * NIN + n0 + i) * DIN + d);
    }
    __syncthreads();

    const float4 bias = *(const float4*)(Bc + cg * DCAP + e0);

    uint32 spk[16][2];                              // packed bf16 s1 accumulator
    #pragma unroll
    for (int b = 0; b < 16; ++b) { spk[b][0] = 0u; spk[b][1] = 0u; }

    const float* wbase = W + (size_t)cg * (DIN * DCAP) + e0;

    for (int i = 0; i < 8; ++i) {
        const int n = n0 + i;
        float4 w[16];
        {
            const float* wp = wbase + (size_t)n * (NCAP * DIN * DCAP);
            #pragma unroll
            for (int d = 0; d < 16; ++d) w[d] = *(const float4*)(wp + d * DCAP);
        }
        const float* xrow = xs + i * 256;
        __hip_bfloat16* ub = u + ((size_t)b0 * NIN + n) * ROW + cg * DCAP + e0;

        #pragma unroll
        for (int bi = 0; bi < 16; ++bi) {
            float4 uv = bias;
            #pragma unroll
            for (int d4 = 0; d4 < 4; ++d4) {
                const float4 xv = *(const float4*)(xrow + bi * 16 + d4 * 4); // broadcast
                uv.x = fmaf(xv.x, w[d4*4+0].x, uv.x);
                uv.y = fmaf(xv.x, w[d4*4+0].y, uv.y);
                uv.z = fmaf(xv.x, w[d4*4+0].z, uv.z);
                uv.w = fmaf(xv.x, w[d4*4+0].w, uv.w);
                uv.x = fmaf(xv.y, w[d4*4+1].x, uv.x);
                uv.y = fmaf(xv.y, w[d4*4+1].y, uv.y);
                uv.z = fmaf(xv.y, w[d4*4+1].z, uv.z);
                uv.w = fmaf(xv.y, w[d4*4+1].w, uv.w);
                uv.x = fmaf(xv.z, w[d4*4+2].x, uv.x);
                uv.y = fmaf(xv.z, w[d4*4+2].y, uv.y);
                uv.z = fmaf(xv.z, w[d4*4+2].z, uv.z);
                uv.w = fmaf(xv.z, w[d4*4+2].w, uv.w);
                uv.x = fmaf(xv.w, w[d4*4+3].x, uv.x);
                uv.y = fmaf(xv.w, w[d4*4+3].y, uv.y);
                uv.z = fmaf(xv.w, w[d4*4+3].z, uv.z);
                uv.w = fmaf(xv.w, w[d4*4+3].w, uv.w);
            }
            uint2 pk;
            pk.x = cvt_pk_bf16(uv.x, uv.y);
            pk.y = cvt_pk_bf16(uv.z, uv.w);
            *(uint2*)(ub + (size_t)bi * (NIN * ROW)) = pk;
            spk[bi][0] = cvt_pk_bf16(bf_lo(spk[bi][0]) + uv.x,
                                     bf_hi(spk[bi][0]) + uv.y);
            spk[bi][1] = cvt_pk_bf16(bf_lo(spk[bi][1]) + uv.z,
                                     bf_hi(spk[bi][1]) + uv.w);
        }
    }

    #pragma unroll
    for (int b = 0; b < 16; ++b) {
        uint2 pk; pk.x = spk[b][0]; pk.y = spk[b][1];
        *(uint2*)(part + ((size_t)(b0 + b) * 256 + chunk) * ROW + cg * DCAP + e0) = pk;
    }
}

// ---------------------------------------------------------------------------
// K2: s[b,p0..p0+3] = factor * sum_ch part[b][ch][p]; v = squash(s);
//     V = (first ? v : V+v); if(out) out = v.  part bf16 or f32 per flag.
// grid = (8, BATCH), block 64; thread owns 4 consecutive p (e-group = 8 lanes)
// ---------------------------------------------------------------------------
__global__ __launch_bounds__(64)
void k2_squash(const void* __restrict__ partv, int nch, int isbf16, float factor,
               float* __restrict__ V, float* __restrict__ out, int first)
{
    const int t  = threadIdx.x;
    const int b  = blockIdx.y;
    const int p0 = (blockIdx.x * 64 + t) * 4;

    float a0 = 0.f, a1 = 0.f, a2 = 0.f, a3 = 0.f;
    if (isbf16) {
        const ushort* pp = (const ushort*)partv;
        #pragma unroll 4
        for (int ch = 0; ch < nch; ++ch) {
            const uint2 v = *(const uint2*)(pp + ((size_t)b * nch + ch) * ROW + p0);
            a0 += bf_lo(v.x); a1 += bf_hi(v.x);
            a2 += bf_lo(v.y); a3 += bf_hi(v.y);
        }
    } else {
        const float* pp = (const float*)partv;
        #pragma unroll 4
        for (int ch = 0; ch < nch; ++ch) {
            const float4 v = *(const float4*)(pp + ((size_t)b * nch + ch) * ROW + p0);
            a0 += v.x; a1 += v.y; a2 += v.z; a3 += v.w;
        }
    }
    a0 *= factor; a1 *= factor; a2 *= factor; a3 *= factor;

    float nsq = a0*a0 + a1*a1 + a2*a2 + a3*a3;
    nsq += __shfl_xor(nsq, 1);
    nsq += __shfl_xor(nsq, 2);
    nsq += __shfl_xor(nsq, 4);                       // 8 lanes × 4 = 32 e
    const float scale = nsq / ((1.f + nsq) * sqrtf(nsq + 1e-9f));
    const float v0 = scale*a0, v1 = scale*a1, v2 = scale*a2, v3 = scale*a3;

    const size_t idx = (size_t)b * ROW + p0;
    float4 Vn;
    if (first) Vn = make_float4(v0, v1, v2, v3);
    else {
        const float4 old = *(const float4*)(V + idx);
        Vn = make_float4(old.x+v0, old.y+v1, old.z+v2, old.w+v3);
    }
    *(float4*)(V + idx) = Vn;
    if (out) *(float4*)(out + idx) = make_float4(v0, v1, v2, v3);
}

// ---------------------------------------------------------------------------
// K3 sweep, COALESCED (R5-proven, unchanged): wave reads u row contiguously;
// lane holds e-slice es=(l&3)*8 of capsules q*16+(l>>2). Quad-shfl logit
// reduce, wave softmax denom (*4), no max-sub. 4-wave blocks, LDS c*33+e
// reduce, f32 partials nch=32.  grid = (32 n-chunks of 64, BATCH), block 256.
// ---------------------------------------------------------------------------
__global__ __launch_bounds__(256)
void k3_sweep(const __hip_bfloat16* __restrict__ u, const float* __restrict__ V,
              float* __restrict__ part)
{
    __shared__ float red[4 * 2112];                  // [wave][c*33+e]
    const int t     = threadIdx.x;
    const int lane  = t & 63;
    const int wv    = t >> 6;
    const int chunk = blockIdx.x;
    const int b     = blockIdx.y;

    const int qr = lane >> 2;                        // 0..15: capsule-in-quarter
    const int es = (lane & 3) * 8;                   // e-slice start

    float vr[4][8];
    #pragma unroll
    for (int q = 0; q < 4; ++q) {
        const float* vp = V + (size_t)b * ROW + (q * 16 + qr) * DCAP + es;
        const float4 v0 = *(const float4*)(vp);
        const float4 v1 = *(const float4*)(vp + 4);
        vr[q][0]=v0.x; vr[q][1]=v0.y; vr[q][2]=v0.z; vr[q][3]=v0.w;
        vr[q][4]=v1.x; vr[q][5]=v1.y; vr[q][6]=v1.z; vr[q][7]=v1.w;
    }

    float sacc[4][8];
    #pragma unroll
    for (int q = 0; q < 4; ++q)
        #pragma unroll
        for (int j = 0; j < 8; ++j) sacc[q][j] = 0.f;

    const int nbase = chunk * 64 + wv * 16;
    const __hip_bfloat16* ubase = u + ((size_t)b * NIN + nbase) * ROW + lane * 8;

    uint4 A[4];
    #pragma unroll
    for (int q = 0; q < 4; ++q)
        A[q] = *(const uint4*)(ubase + q * 512);

    for (int it = 0; it < 16; ++it) {
        uint4 Bn[4];
        if (it < 15) {
            const __hip_bfloat16* un = ubase + (size_t)(it + 1) * ROW;
            #pragma unroll
            for (int q = 0; q < 4; ++q)
                Bn[q] = *(const uint4*)(un + q * 512);
        }

        float p[4];
        #pragma unroll
        for (int q = 0; q < 4; ++q) {
            const uint32 w0 = A[q].x, w1 = A[q].y, w2 = A[q].z, w3 = A[q].w;
            float l0 = bf_lo(w0) * vr[q][0];
            float l1 = bf_hi(w0) * vr[q][1];
            l0 = fmaf(bf_lo(w1), vr[q][2], l0);
            l1 = fmaf(bf_hi(w1), vr[q][3], l1);
            l0 = fmaf(bf_lo(w2), vr[q][4], l0);
            l1 = fmaf(bf_hi(w2), vr[q][5], l1);
            l0 = fmaf(bf_lo(w3), vr[q][6], l0);
            l1 = fmaf(bf_hi(w3), vr[q][7], l1);
            p[q] = l0 + l1;
        }
        #pragma unroll
        for (int q = 0; q < 4; ++q) {
            p[q] += __shfl_xor(p[q], 1);
            p[q] += __shfl_xor(p[q], 2);
        }
        float e0 = __expf(p[0]), e1 = __expf(p[1]),
              e2 = __expf(p[2]), e3 = __expf(p[3]);
        float s = (e0 + e1) + (e2 + e3);
        s += __shfl_xor(s, 4);
        s += __shfl_xor(s, 8);
        s += __shfl_xor(s, 16);
        s += __shfl_xor(s, 32);                      // s = 4 * sum_c exp
        const float inv = 4.0f / s;
        const float cw[4] = {e0 * inv, e1 * inv, e2 * inv, e3 * inv};

        #pragma unroll
        for (int q = 0; q < 4; ++q) {
            const uint32 w0 = A[q].x, w1 = A[q].y, w2 = A[q].z, w3 = A[q].w;
            const float c = cw[q];
            sacc[q][0] = fmaf(c, bf_lo(w0), sacc[q][0]);
            sacc[q][1] = fmaf(c, bf_hi(w0), sacc[q][1]);
            sacc[q][2] = fmaf(c, bf_lo(w1), sacc[q][2]);
            sacc[q][3] = fmaf(c, bf_hi(w1), sacc[q][3]);
            sacc[q][4] = fmaf(c, bf_lo(w2), sacc[q][4]);
            sacc[q][5] = fmaf(c, bf_hi(w2), sacc[q][5]);
            sacc[q][6] = fmaf(c, bf_lo(w3), sacc[q][6]);
            sacc[q][7] = fmaf(c, bf_hi(w3), sacc[q][7]);
        }

        if (it < 15) {
            #pragma unroll
            for (int q = 0; q < 4; ++q) A[q] = Bn[q];
        }
    }

    #pragma unroll
    for (int q = 0; q < 4; ++q) {
        const int c = q * 16 + qr;
        #pragma unroll
        for (int j = 0; j < 8; ++j)
            red[wv * 2112 + c * 33 + es + j] = sacc[q][j];
    }
    __syncthreads();
    #pragma unroll
    for (int k = 0; k < 8; ++k) {
        const int pp = t + 256 * k;
        const int c = pp >> 5, e = pp & 31;
        part[((size_t)b * 32 + chunk) * ROW + pp] =
            red[0*2112 + c*33+e] + red[1*2112 + c*33+e] +
            red[2*2112 + c*33+e] + red[3*2112 + c*33+e];
    }
}

// ---------------------------------------------------------------------------
extern "C" void kernel_launch(void* const* d_in, const int* in_sizes, int n_in,
                              void* d_out, int out_size, void* d_ws, size_t ws_size,
                              hipStream_t stream)
{
    const float* x  = (const float*)d_in[0];
    const float* W  = (const float*)d_in[1];
    const float* Bc = (const float*)d_in[2];
    float* out = (float*)d_out;

    const size_t off_u    = 0;                       // u: 32*2048*2048 bf16 = 256 MiB
    const size_t off_part = 268435456;               // part: 32 MiB max
    const size_t off_V    = off_part + 33554432;     // V: 32*64*32 f32
    const size_t need     = off_V + 262144;
    if (ws_size < need) return;

    __hip_bfloat16* u  = (__hip_bfloat16*)((char*)d_ws + off_u);
    ushort* part_bf    = (ushort*)((char*)d_ws + off_part);
    float*  part_f     = (float*)((char*)d_ws + off_part);   // aliased: consumed before k3 writes
    float*  V          = (float*)((char*)d_ws + off_V);

    // iter 1: u + uniform-softmax s1 fused (bf16 partials)
    k1_predict<<<dim3(4, 256), 256, 0, stream>>>(x, W, Bc, u, part_bf);
    k2_squash <<<dim3(8, BATCH), 64, 0, stream>>>(part_bf, 256, 1, 1.0f/64.0f, V, nullptr, 1);
    // iter 2: logits = u.V (V=v1), softmax, s2
    k3_sweep  <<<dim3(32, BATCH), 256, 0, stream>>>(u, V, part_f);
    k2_squash <<<dim3(8, BATCH), 64, 0, stream>>>(part_f, 32, 0, 1.0f, V, nullptr, 0);
    // iter 3: logits = u.(v1+v2), softmax, s3 -> v3 = output
    k3_sweep  <<<dim3(32, BATCH), 256, 0, stream>>>(u, V, part_f);
    k2_squash <<<dim3(8, BATCH), 64, 0, stream>>>(part_f, 32, 0, 1.0f, V, out, 0);
}

// Round 13
// 262.597 us; speedup vs baseline: 2.7066x; 1.1795x over previous
//
#include <hip/hip_runtime.h>
#include <hip/hip_bf16.h>

typedef unsigned int uint32;

#define BATCH 32
#define NIN   2048
#define DIN   16
#define NCAP  64
#define DCAP  32
#define ROW   2048   // NCAP*DCAP

__device__ __forceinline__ uint32 pack_bf2(float a, float b){
    union { __hip_bfloat16 h; ushort u; } ca, cb;
    ca.h = __float2bfloat16(a);
    cb.h = __float2bfloat16(b);
    return (uint32)ca.u | ((uint32)cb.u << 16);
}
__device__ __forceinline__ float bf_lo(uint32 w){ return __uint_as_float(w << 16); }
__device__ __forceinline__ float bf_hi(uint32 w){ return __uint_as_float(w & 0xffff0000u); }

// ---------------------------------------------------------------------------
// K1 (R2/R5-proven, ~150us): u[b,n,c,e] = sum_d x[b,n,d]*W[n,c,d,e] + B[c,e]
//     + s1 partials (bf16): part[b][chunk][ce] = sum_{n in chunk} u
// grid = (2 ce-halves, 256 chunks of 8 n), block 256; thread owns (c, 4 e's).
// 8 k1 experiments (2e, b-splits, prefetch, MFMA-naive, scalar-x) all landed
// neutral-or-worse; this shape is the empirical optimum.
// ---------------------------------------------------------------------------
__global__ __launch_bounds__(256, 2)
void k1_predict(const float* __restrict__ x, const float* __restrict__ W,
                const float* __restrict__ Bc, __hip_bfloat16* __restrict__ u,
                ushort* __restrict__ part)
{
    __shared__ float xs[8 * 32 * 16];               // [i][b][d], 16 KB
    const int t     = threadIdx.x;
    const int half  = blockIdx.x;                   // ce-half
    const int chunk = blockIdx.y;                   // 0..255, 8 n each
    const int n0    = chunk * 8;
    const int cl    = t >> 3;                       // 0..31 local capsule
    const int e0    = (t & 7) * 4;                  // 4 consecutive e
    const int cg    = half * 32 + cl;               // global capsule

    #pragma unroll
    for (int k = 0; k < 4; ++k) {
        const int f = (t + 256 * k) * 4;
        const int i = f >> 9, rem = f & 511, b = rem >> 4, d = rem & 15;
        *(float4*)(xs + f) = *(const float4*)(x + ((size_t)b * NIN + n0 + i) * DIN + d);
    }
    __syncthreads();

    const float4 bias = *(const float4*)(Bc + cg * DCAP + e0);

    float sacc[32][4];
    #pragma unroll
    for (int b = 0; b < 32; ++b) {
        sacc[b][0] = 0.f; sacc[b][1] = 0.f; sacc[b][2] = 0.f; sacc[b][3] = 0.f;
    }

    const float* wbase = W + (size_t)cg * (DIN * DCAP) + e0;
    for (int i = 0; i < 8; ++i) {
        const int n = n0 + i;
        float4 w[16];
        {
            const float* wp = wbase + (size_t)n * (NCAP * DIN * DCAP);
            #pragma unroll
            for (int d = 0; d < 16; ++d) w[d] = *(const float4*)(wp + d * DCAP);
        }
        const float* xrow = xs + i * 512;
        __hip_bfloat16* ub = u + (size_t)n * ROW + cg * DCAP + e0;

        #pragma unroll
        for (int b = 0; b < 32; ++b) {
            float4 uv = bias;
            #pragma unroll
            for (int d4 = 0; d4 < 4; ++d4) {
                const float4 xv = *(const float4*)(xrow + b * 16 + d4 * 4);  // broadcast
                uv.x = fmaf(xv.x, w[d4*4+0].x, uv.x);
                uv.y = fmaf(xv.x, w[d4*4+0].y, uv.y);
                uv.z = fmaf(xv.x, w[d4*4+0].z, uv.z);
                uv.w = fmaf(xv.x, w[d4*4+0].w, uv.w);
                uv.x = fmaf(xv.y, w[d4*4+1].x, uv.x);
                uv.y = fmaf(xv.y, w[d4*4+1].y, uv.y);
                uv.z = fmaf(xv.y, w[d4*4+1].z, uv.z);
                uv.w = fmaf(xv.y, w[d4*4+1].w, uv.w);
                uv.x = fmaf(xv.z, w[d4*4+2].x, uv.x);
                uv.y = fmaf(xv.z, w[d4*4+2].y, uv.y);
                uv.z = fmaf(xv.z, w[d4*4+2].z, uv.z);
                uv.w = fmaf(xv.z, w[d4*4+2].w, uv.w);
                uv.x = fmaf(xv.w, w[d4*4+3].x, uv.x);
                uv.y = fmaf(xv.w, w[d4*4+3].y, uv.y);
                uv.z = fmaf(xv.w, w[d4*4+3].z, uv.z);
                uv.w = fmaf(xv.w, w[d4*4+3].w, uv.w);
            }
            sacc[b][0] += uv.x; sacc[b][1] += uv.y;
            sacc[b][2] += uv.z; sacc[b][3] += uv.w;
            uint2 pk;
            pk.x = pack_bf2(uv.x, uv.y);
            pk.y = pack_bf2(uv.z, uv.w);
            *(uint2*)(ub + (size_t)b * (NIN * ROW)) = pk;
        }
    }

    #pragma unroll
    for (int b = 0; b < 32; ++b) {
        uint2 pk;
        pk.x = pack_bf2(sacc[b][0], sacc[b][1]);
        pk.y = pack_bf2(sacc[b][2], sacc[b][3]);
        *(uint2*)(part + ((size_t)b * 256 + chunk) * ROW + cg * DCAP + e0) = pk;
    }
}

// ---------------------------------------------------------------------------
// K2: s[b,p0..p0+3] = factor * sum_ch part[b][ch][p]; v = squash(s);
//     V = (first ? v : V+v); if(out) out = v.  part bf16 or f32 per flag.
// grid = (8, BATCH), block 64; thread owns 4 consecutive p (e-group = 8 lanes)
// ---------------------------------------------------------------------------
__global__ __launch_bounds__(64)
void k2_squash(const void* __restrict__ partv, int nch, int isbf16, float factor,
               float* __restrict__ V, float* __restrict__ out, int first)
{
    const int t  = threadIdx.x;
    const int b  = blockIdx.y;
    const int p0 = (blockIdx.x * 64 + t) * 4;

    float a0 = 0.f, a1 = 0.f, a2 = 0.f, a3 = 0.f;
    if (isbf16) {
        const ushort* pp = (const ushort*)partv;
        #pragma unroll 4
        for (int ch = 0; ch < nch; ++ch) {
            const uint2 v = *(const uint2*)(pp + ((size_t)b * nch + ch) * ROW + p0);
            a0 += bf_lo(v.x); a1 += bf_hi(v.x);
            a2 += bf_lo(v.y); a3 += bf_hi(v.y);
        }
    } else {
        const float* pp = (const float*)partv;
        #pragma unroll 4
        for (int ch = 0; ch < nch; ++ch) {
            const float4 v = *(const float4*)(pp + ((size_t)b * nch + ch) * ROW + p0);
            a0 += v.x; a1 += v.y; a2 += v.z; a3 += v.w;
        }
    }
    a0 *= factor; a1 *= factor; a2 *= factor; a3 *= factor;

    float nsq = a0*a0 + a1*a1 + a2*a2 + a3*a3;
    nsq += __shfl_xor(nsq, 1);
    nsq += __shfl_xor(nsq, 2);
    nsq += __shfl_xor(nsq, 4);                       // 8 lanes × 4 = 32 e
    const float scale = nsq / ((1.f + nsq) * sqrtf(nsq + 1e-9f));
    const float v0 = scale*a0, v1 = scale*a1, v2 = scale*a2, v3 = scale*a3;

    const size_t idx = (size_t)b * ROW + p0;
    float4 Vn;
    if (first) Vn = make_float4(v0, v1, v2, v3);
    else {
        const float4 old = *(const float4*)(V + idx);
        Vn = make_float4(old.x+v0, old.y+v1, old.z+v2, old.w+v3);
    }
    *(float4*)(V + idx) = Vn;
    if (out) *(float4*)(out + idx) = make_float4(v0, v1, v2, v3);
}

// ---------------------------------------------------------------------------
// K3 sweep, COALESCED (R5-proven): wave reads u row contiguously; lane holds
// e-slice es=(l&3)*8 of capsules q*16+(l>>2). Quad-shfl logit reduce, wave
// softmax denom (*4), no max-sub (|logit|<~12). 4-wave blocks, LDS c*33+e
// reduce, f32 partials nch=32.  grid = (32 n-chunks of 64, BATCH), block 256.
// ---------------------------------------------------------------------------
__global__ __launch_bounds__(256)
void k3_sweep(const __hip_bfloat16* __restrict__ u, const float* __restrict__ V,
              float* __restrict__ part)
{
    __shared__ float red[4 * 2112];                  // [wave][c*33+e]
    const int t     = threadIdx.x;
    const int lane  = t & 63;
    const int wv    = t >> 6;
    const int chunk = blockIdx.x;
    const int b     = blockIdx.y;

    const int qr = lane >> 2;                        // 0..15: capsule-in-quarter
    const int es = (lane & 3) * 8;                   // e-slice start

    float vr[4][8];
    #pragma unroll
    for (int q = 0; q < 4; ++q) {
        const float* vp = V + (size_t)b * ROW + (q * 16 + qr) * DCAP + es;
        const float4 v0 = *(const float4*)(vp);
        const float4 v1 = *(const float4*)(vp + 4);
        vr[q][0]=v0.x; vr[q][1]=v0.y; vr[q][2]=v0.z; vr[q][3]=v0.w;
        vr[q][4]=v1.x; vr[q][5]=v1.y; vr[q][6]=v1.z; vr[q][7]=v1.w;
    }

    float sacc[4][8];
    #pragma unroll
    for (int q = 0; q < 4; ++q)
        #pragma unroll
        for (int j = 0; j < 8; ++j) sacc[q][j] = 0.f;

    const int nbase = chunk * 64 + wv * 16;
    const __hip_bfloat16* ubase = u + ((size_t)b * NIN + nbase) * ROW + lane * 8;

    uint4 A[4];
    #pragma unroll
    for (int q = 0; q < 4; ++q)
        A[q] = *(const uint4*)(ubase + q * 512);

    for (int it = 0; it < 16; ++it) {
        uint4 Bn[4];
        if (it < 15) {
            const __hip_bfloat16* un = ubase + (size_t)(it + 1) * ROW;
            #pragma unroll
            for (int q = 0; q < 4; ++q)
                Bn[q] = *(const uint4*)(un + q * 512);
        }

        float p[4];
        #pragma unroll
        for (int q = 0; q < 4; ++q) {
            const uint32 w0 = A[q].x, w1 = A[q].y, w2 = A[q].z, w3 = A[q].w;
            float l0 = bf_lo(w0) * vr[q][0];
            float l1 = bf_hi(w0) * vr[q][1];
            l0 = fmaf(bf_lo(w1), vr[q][2], l0);
            l1 = fmaf(bf_hi(w1), vr[q][3], l1);
            l0 = fmaf(bf_lo(w2), vr[q][4], l0);
            l1 = fmaf(bf_hi(w2), vr[q][5], l1);
            l0 = fmaf(bf_lo(w3), vr[q][6], l0);
            l1 = fmaf(bf_hi(w3), vr[q][7], l1);
            p[q] = l0 + l1;
        }
        #pragma unroll
        for (int q = 0; q < 4; ++q) {
            p[q] += __shfl_xor(p[q], 1);
            p[q] += __shfl_xor(p[q], 2);
        }
        float e0 = __expf(p[0]), e1 = __expf(p[1]),
              e2 = __expf(p[2]), e3 = __expf(p[3]);
        float s = (e0 + e1) + (e2 + e3);
        s += __shfl_xor(s, 4);
        s += __shfl_xor(s, 8);
        s += __shfl_xor(s, 16);
        s += __shfl_xor(s, 32);                      // s = 4 * sum_c exp
        const float inv = 4.0f / s;
        const float cw[4] = {e0 * inv, e1 * inv, e2 * inv, e3 * inv};

        #pragma unroll
        for (int q = 0; q < 4; ++q) {
            const uint32 w0 = A[q].x, w1 = A[q].y, w2 = A[q].z, w3 = A[q].w;
            const float c = cw[q];
            sacc[q][0] = fmaf(c, bf_lo(w0), sacc[q][0]);
            sacc[q][1] = fmaf(c, bf_hi(w0), sacc[q][1]);
            sacc[q][2] = fmaf(c, bf_lo(w1), sacc[q][2]);
            sacc[q][3] = fmaf(c, bf_hi(w1), sacc[q][3]);
            sacc[q][4] = fmaf(c, bf_lo(w2), sacc[q][4]);
            sacc[q][5] = fmaf(c, bf_hi(w2), sacc[q][5]);
            sacc[q][6] = fmaf(c, bf_lo(w3), sacc[q][6]);
            sacc[q][7] = fmaf(c, bf_hi(w3), sacc[q][7]);
        }

        if (it < 15) {
            #pragma unroll
            for (int q = 0; q < 4; ++q) A[q] = Bn[q];
        }
    }

    #pragma unroll
    for (int q = 0; q < 4; ++q) {
        const int c = q * 16 + qr;
        #pragma unroll
        for (int j = 0; j < 8; ++j)
            red[wv * 2112 + c * 33 + es + j] = sacc[q][j];
    }
    __syncthreads();
    #pragma unroll
    for (int k = 0; k < 8; ++k) {
        const int pp = t + 256 * k;
        const int c = pp >> 5, e = pp & 31;
        part[((size_t)b * 32 + chunk) * ROW + pp] =
            red[0*2112 + c*33+e] + red[1*2112 + c*33+e] +
            red[2*2112 + c*33+e] + red[3*2112 + c*33+e];
    }
}

// ---------------------------------------------------------------------------
extern "C" void kernel_launch(void* const* d_in, const int* in_sizes, int n_in,
                              void* d_out, int out_size, void* d_ws, size_t ws_size,
                              hipStream_t stream)
{
    const float* x  = (const float*)d_in[0];
    const float* W  = (const float*)d_in[1];
    const float* Bc = (const float*)d_in[2];
    float* out = (float*)d_out;

    const size_t off_u    = 0;                       // u: 32*2048*2048 bf16 = 256 MiB
    const size_t off_part = 268435456;               // part: 32 MiB max
    const size_t off_V    = off_part + 33554432;     // V: 32*64*32 f32
    const size_t need     = off_V + 262144;
    if (ws_size < need) return;

    __hip_bfloat16* u  = (__hip_bfloat16*)((char*)d_ws + off_u);
    ushort* part_bf    = (ushort*)((char*)d_ws + off_part);
    float*  part_f     = (float*)((char*)d_ws + off_part);   // aliased: consumed before k3 writes
    float*  V          = (float*)((char*)d_ws + off_V);

    // iter 1: u + uniform-softmax s1 fused (bf16 partials)
    k1_predict<<<dim3(2, 256), 256, 0, stream>>>(x, W, Bc, u, part_bf);
    k2_squash <<<dim3(8, BATCH), 64, 0, stream>>>(part_bf, 256, 1, 1.0f/64.0f, V, nullptr, 1);
    // iter 2: logits = u.V (V=v1), softmax, s2
    k3_sweep  <<<dim3(32, BATCH), 256, 0, stream>>>(u, V, part_f);
    k2_squash <<<dim3(8, BATCH), 64, 0, stream>>>(part_f, 32, 0, 1.0f, V, nullptr, 0);
    // iter 3: logits = u.(v1+v2), softmax, s3 -> v3 = output
    k3_sweep  <<<dim3(32, BATCH), 256, 0, stream>>>(u, V, part_f);
    k2_squash <<<dim3(8, BATCH), 64, 0, stream>>>(part_f, 32, 0, 1.0f, V, out, 0);
}